// Round 2
// baseline (396.508 us; speedup 1.0000x reference)
//
#include <hip/hip_runtime.h>

typedef __attribute__((ext_vector_type(8))) short short8;
typedef __attribute__((ext_vector_type(4))) float f32x4;

#define MFMA16(a, b, c) __builtin_amdgcn_mfma_f32_16x16x32_bf16((a), (b), (c), 0, 0, 0)

__device__ __forceinline__ unsigned short f2b(float f) {
  union { float f; unsigned u; } v; v.f = f;
  return (unsigned short)((v.u + 0x7FFFu + ((v.u >> 16) & 1u)) >> 16);  // RNE
}

// ---------------- prep kernels ----------------
// wqkvT[wcol][k] = bf16(qkv_w[k][wcol]) with SCALE folded into Q columns (wcol<256)
__global__ void prep_wqkv(const float* __restrict__ qkv_w, unsigned short* __restrict__ wq) {
  int idx = blockIdx.x * 256 + threadIdx.x;   // 768*256
  int wcol = idx >> 8, k = idx & 255;
  float v = qkv_w[k * 768 + wcol];
  if (wcol < 256) v *= 0.125f;
  wq[idx] = f2b(v);
}

__global__ void prep_wproj(const float* __restrict__ proj_w, unsigned short* __restrict__ wp) {
  int idx = blockIdx.x * 256 + threadIdx.x;   // 256*256
  int col = idx >> 8, k = idx & 255;
  wp[idx] = f2b(proj_w[k * 256 + col]);
}

// comb[w][h][i][j] (64x4x64x64 f32): mask+bias for valid, 0 for pad rows, -1e30 for pad cols
__global__ void prep_comb(const float* __restrict__ mask, const float* __restrict__ bias_table,
                          const int* __restrict__ rel_index, float* __restrict__ comb) {
  int idx = blockIdx.x * 256 + threadIdx.x;   // 64*4*64*64 = 1048576
  int j = idx & 63, i = (idx >> 6) & 63, h = (idx >> 12) & 3, w = idx >> 14;
  float v;
  if (j >= 49) v = -1e30f;
  else if (i >= 49) v = 0.f;
  else v = mask[(w * 49 + i) * 49 + j] + bias_table[rel_index[i * 49 + j] * 4 + h];
  comb[idx] = v;
}

// ---------------- fused window-attention kernel ----------------
// LDS (ushort units), exact strides + XOR swizzle (col ^= (row&7)<<3) on every tile.
#define XS   0        // [64][256]  x bf16; later aliased by attention output O
#define QS   16384    // [64][64]   Q
#define KS   20480    // [64][64]   K
#define VT   24576    // [64][64]   V transposed: [dim][token]
#define PS   28672    // [64][64]   P (softmax probs), per-wave row slices
#define LDS_TOT 32768 // ushorts = 65536 B -> 2 blocks/CU

__device__ __forceinline__ int xsw(int row, int col) { return row * 256 + (col ^ ((row & 7) << 3)); }
__device__ __forceinline__ int tsw(int row, int col) { return row * 64  + (col ^ ((row & 7) << 3)); }

__global__ __launch_bounds__(256, 2) void win_attn(
    const float* __restrict__ x, const float* __restrict__ qkv_b,
    const float* __restrict__ proj_b, const unsigned short* __restrict__ wq,
    const unsigned short* __restrict__ wp, const float* __restrict__ comb,
    float* __restrict__ out)
{
  __shared__ alignas(16) unsigned short lds[LDS_TOT];
  const int b = blockIdx.x, tid = threadIdx.x;
  const int wv = tid >> 6, l = tid & 63, g = l >> 4, c = l & 15;

  // ---- Phase A: stage x[b] -> bf16 LDS (swizzled), rows >= 49 zeroed ----
  {
    const float* xb = x + (size_t)b * (49 * 256);
    #pragma unroll
    for (int it = 0; it < 8; ++it) {
      int idx = tid + it * 256, row = idx >> 5, c8 = idx & 31;  // 8-float chunks
      float4 v0 = make_float4(0.f, 0.f, 0.f, 0.f), v1 = v0;
      if (row < 49) {
        const float4* p = (const float4*)(xb + row * 256 + c8 * 8);
        v0 = p[0]; v1 = p[1];
      }
      short8 pk;
      pk[0] = f2b(v0.x); pk[1] = f2b(v0.y); pk[2] = f2b(v0.z); pk[3] = f2b(v0.w);
      pk[4] = f2b(v1.x); pk[5] = f2b(v1.y); pk[6] = f2b(v1.z); pk[7] = f2b(v1.w);
      *(short8*)&lds[XS + xsw(row, c8 * 8)] = pk;
    }
  }
  __syncthreads();

  const f32x4 zero4 = {0.f, 0.f, 0.f, 0.f};
  f32x4 oacc[4][4];
  #pragma unroll
  for (int h = 0; h < 4; ++h)
    #pragma unroll
    for (int nd = 0; nd < 4; ++nd) oacc[h][nd] = zero4;

  #pragma unroll
  for (int h = 0; h < 4; ++h) {
    // ---- B1: QKV GEMM for head h; wave computes 16-col slice of Q,K,V ----
    f32x4 acc[3][4];
    #pragma unroll
    for (int dst = 0; dst < 3; ++dst)
      #pragma unroll
      for (int mi = 0; mi < 4; ++mi) acc[dst][mi] = zero4;

    const unsigned short* wbase = wq + ((size_t)(h * 64 + wv * 16 + c)) * 256 + g * 8;
    #pragma unroll
    for (int ks = 0; ks < 8; ++ks) {
      short8 bf0 = *(const short8*)(wbase + ks * 32);            // Q weights
      short8 bf1 = *(const short8*)(wbase + 65536 + ks * 32);    // K weights
      short8 bf2 = *(const short8*)(wbase + 131072 + ks * 32);   // V weights
      #pragma unroll
      for (int mi = 0; mi < 4; ++mi) {
        short8 af = *(const short8*)&lds[XS + xsw(mi * 16 + c, ks * 32 + g * 8)];
        acc[0][mi] = MFMA16(af, bf0, acc[0][mi]);
        acc[1][mi] = MFMA16(af, bf1, acc[1][mi]);
        acc[2][mi] = MFMA16(af, bf2, acc[2][mi]);
      }
    }
    const float bq = qkv_b[h * 64 + wv * 16 + c] * 0.125f;   // SCALE folded into Q path
    const float bk = qkv_b[256 + h * 64 + wv * 16 + c];
    const float bv = qkv_b[512 + h * 64 + wv * 16 + c];
    const int d = wv * 16 + c;
    #pragma unroll
    for (int mi = 0; mi < 4; ++mi) {
      #pragma unroll
      for (int r = 0; r < 4; ++r) {
        const int row = mi * 16 + g * 4 + r;
        lds[QS + tsw(row, d)] = f2b(acc[0][mi][r] + bq);
        lds[KS + tsw(row, d)] = f2b(acc[1][mi][r] + bk);
      }
      ushort4 vp;
      vp.x = f2b(acc[2][mi][0] + bv); vp.y = f2b(acc[2][mi][1] + bv);
      vp.z = f2b(acc[2][mi][2] + bv); vp.w = f2b(acc[2][mi][3] + bv);
      *(ushort4*)&lds[VT + tsw(d, mi * 16 + g * 4)] = vp;   // V transposed, packed
    }
    __syncthreads();

    // ---- comb prefetch (hide L2 latency under B2 MFMAs) ----
    const float* cb = comb + (((size_t)(b & 63)) * 4 + h) * 4096;
    float cbv[4][4];
    #pragma unroll
    for (int ni = 0; ni < 4; ++ni)
      #pragma unroll
      for (int r = 0; r < 4; ++r)
        cbv[ni][r] = cb[(wv * 16 + g * 4 + r) * 64 + ni * 16 + c];

    // ---- B2: S = Q K^T for this wave's 16 query rows ----
    f32x4 sacc[4];
    #pragma unroll
    for (int ni = 0; ni < 4; ++ni) sacc[ni] = zero4;
    #pragma unroll
    for (int kk = 0; kk < 2; ++kk) {
      short8 af = *(const short8*)&lds[QS + tsw(wv * 16 + c, kk * 32 + g * 8)];
      #pragma unroll
      for (int ni = 0; ni < 4; ++ni) {
        short8 bf = *(const short8*)&lds[KS + tsw(ni * 16 + c, kk * 32 + g * 8)];
        sacc[ni] = MFMA16(af, bf, sacc[ni]);
      }
    }

    // ---- B3: +bias+mask, row softmax, P -> LDS ----
    float sv[4][4];
    #pragma unroll
    for (int ni = 0; ni < 4; ++ni)
      #pragma unroll
      for (int r = 0; r < 4; ++r)
        sv[ni][r] = sacc[ni][r] + cbv[ni][r];

    #pragma unroll
    for (int r = 0; r < 4; ++r) {
      float m = fmaxf(fmaxf(sv[0][r], sv[1][r]), fmaxf(sv[2][r], sv[3][r]));
      #pragma unroll
      for (int off = 8; off; off >>= 1) m = fmaxf(m, __shfl_xor(m, off, 16));
      float p[4], s = 0.f;
      #pragma unroll
      for (int ni = 0; ni < 4; ++ni) { p[ni] = __expf(sv[ni][r] - m); s += p[ni]; }
      #pragma unroll
      for (int off = 8; off; off >>= 1) s += __shfl_xor(s, off, 16);
      const float inv = 1.0f / s;
      const int row = wv * 16 + g * 4 + r;
      #pragma unroll
      for (int ni = 0; ni < 4; ++ni)
        lds[PS + tsw(row, ni * 16 + c)] = f2b(p[ni] * inv);
    }

    // ---- B4: O_h = P V (accumulate per-head in regs) ----
    #pragma unroll
    for (int kk = 0; kk < 2; ++kk) {
      short8 af = *(const short8*)&lds[PS + tsw(wv * 16 + c, kk * 32 + g * 8)];
      #pragma unroll
      for (int nd = 0; nd < 4; ++nd) {
        short8 bf = *(const short8*)&lds[VT + tsw(nd * 16 + c, kk * 32 + g * 8)];
        oacc[h][nd] = MFMA16(af, bf, oacc[h][nd]);
      }
    }
    __syncthreads();   // protect QS/KS/VT/XS before next head / phase C
  }

  // ---- Phase C: write O bf16 into XS region (x is dead now) ----
  #pragma unroll
  for (int h = 0; h < 4; ++h)
    #pragma unroll
    for (int nd = 0; nd < 4; ++nd)
      #pragma unroll
      for (int r = 0; r < 4; ++r)
        lds[XS + xsw(wv * 16 + g * 4 + r, h * 64 + nd * 16 + c)] = f2b(oacc[h][nd][r]);
  __syncthreads();

  // ---- Phase D: out = O @ proj_w + proj_b (k-outer: A-frags shared by 4 col-tiles) ----
  f32x4 pacc[4][4];   // [nj][mi]
  #pragma unroll
  for (int nj = 0; nj < 4; ++nj)
    #pragma unroll
    for (int mi = 0; mi < 4; ++mi) pacc[nj][mi] = zero4;

  const unsigned short* wpb = wp + ((size_t)(wv * 64 + c)) * 256 + g * 8;
  #pragma unroll
  for (int ks = 0; ks < 8; ++ks) {
    short8 bfj[4];
    #pragma unroll
    for (int nj = 0; nj < 4; ++nj)
      bfj[nj] = *(const short8*)(wpb + (size_t)nj * 16 * 256 + ks * 32);
    #pragma unroll
    for (int mi = 0; mi < 4; ++mi) {
      short8 af = *(const short8*)&lds[XS + xsw(mi * 16 + c, ks * 32 + g * 8)];
      #pragma unroll
      for (int nj = 0; nj < 4; ++nj)
        pacc[nj][mi] = MFMA16(af, bfj[nj], pacc[nj][mi]);
    }
  }
  #pragma unroll
  for (int nj = 0; nj < 4; ++nj) {
    const float pb = proj_b[wv * 64 + nj * 16 + c];
    #pragma unroll
    for (int mi = 0; mi < 4; ++mi) {
      #pragma unroll
      for (int r = 0; r < 4; ++r) {
        const int row = mi * 16 + g * 4 + r;
        if (row < 49)
          out[((size_t)b * 49 + row) * 256 + wv * 64 + nj * 16 + c] = pacc[nj][mi][r] + pb;
      }
    }
  }
}

extern "C" void kernel_launch(void* const* d_in, const int* in_sizes, int n_in,
                              void* d_out, int out_size, void* d_ws, size_t ws_size,
                              hipStream_t stream) {
  const float* x          = (const float*)d_in[0];
  const float* mask       = (const float*)d_in[1];
  const float* qkv_w      = (const float*)d_in[2];
  const float* qkv_b      = (const float*)d_in[3];
  const float* proj_w     = (const float*)d_in[4];
  const float* proj_b     = (const float*)d_in[5];
  const float* bias_table = (const float*)d_in[6];
  const int*   rel_index  = (const int*)d_in[7];
  float* out = (float*)d_out;

  unsigned short* wq = (unsigned short*)d_ws;            // 768*256 bf16
  unsigned short* wp = wq + 768 * 256;                   // 256*256 bf16
  float* comb = (float*)(wp + 256 * 256);                // 64*4*64*64 f32 (~4 MB)

  prep_wqkv<<<768, 256, 0, stream>>>(qkv_w, wq);
  prep_wproj<<<256, 256, 0, stream>>>(proj_w, wp);
  prep_comb<<<4096, 256, 0, stream>>>(mask, bias_table, rel_index, comb);
  win_attn<<<4096, 256, 0, stream>>>(x, qkv_b, proj_b, wq, wp, comb, out);
}